// Round 1
// baseline (2471.131 us; speedup 1.0000x reference)
//
#include <hip/hip_runtime.h>
#include <hip/hip_bf16.h>
#include <math.h>

// ---------------- problem constants ----------------
#define B_       8
#define T_       2048
#define N_TOK    (B_*T_)        // 16384 tokens
#define D_       1024
#define E_       8
#define H_       4096
#define LS_      1824
#define TOPK     2
#define R_       (N_TOK*TOPK)   // 32768 gathered rows (exact: every token picks 2)
#define OUT_ELEMS ((size_t)N_TOK*D_)  // 16777216

// ---------------- GEMM tiling ----------------
#define BM 128
#define BN 128
#define BK 32
#define MAXT 264                 // sum_e ceil(n_e/128) <= 256+7; 264 is safe static bound
#define PADROWS (MAXT*BM)        // 33792 padded rows for H

typedef __attribute__((ext_vector_type(8))) short short8;
typedef __attribute__((ext_vector_type(4))) float floatx4;

__device__ __forceinline__ unsigned short f2bf(float f) {
  union { float f; unsigned int u; } v; v.f = f;
  unsigned int u = v.u;
  u += 0x7FFFu + ((u >> 16) & 1u);   // round-to-nearest-even
  return (unsigned short)(u >> 16);
}

__device__ __forceinline__ float gelu_tanh(float v) {
  float c = v + 0.044715f * v * v * v;
  return 0.5f * v * (1.0f + tanhf(0.7978845608028654f * c));
}

// ---------------- router: one wave per token ----------------
__global__ __launch_bounds__(256) void router_kernel(
    const float* __restrict__ x, const int* __restrict__ city_idx_p,
    const float* __restrict__ dt, const float* __restrict__ dd,
    const float* __restrict__ drg, const float* __restrict__ de,
    const float* __restrict__ cemb, const float* __restrict__ Wr,
    const float* __restrict__ br,
    float* __restrict__ gate1, int* __restrict__ topk_e,
    float* __restrict__ topk_w, int* __restrict__ counts)
{
  const int wid = threadIdx.x >> 6, lane = threadIdx.x & 63;
  const int token = blockIdx.x * 4 + wid;

  float acc[E_];
#pragma unroll
  for (int e = 0; e < E_; e++) acc[e] = 0.f;

  const float* ce = cemb + (*city_idx_p) * 32;

  auto fma_seg = [&](const float* src, int len, int base) {
    for (int i = lane; i < len; i += 64) {
      float f = src[i];
      const float* w = Wr + (size_t)(base + i) * E_;
      float4 w0 = *(const float4*)w;
      float4 w1 = *(const float4*)(w + 4);
      acc[0] += f * w0.x; acc[1] += f * w0.y; acc[2] += f * w0.z; acc[3] += f * w0.w;
      acc[4] += f * w1.x; acc[5] += f * w1.y; acc[6] += f * w1.z; acc[7] += f * w1.w;
    }
  };
  fma_seg(x  + (size_t)token * D_,  D_,  0);
  fma_seg(ce,                        32, 1024);
  fma_seg(dt + (size_t)token * 256, 256, 1056);
  fma_seg(dd + (size_t)token * 256, 256, 1312);
  fma_seg(drg+ (size_t)token * 128, 128, 1568);
  fma_seg(de + (size_t)token * 128, 128, 1696);

#pragma unroll
  for (int e = 0; e < E_; e++) {
    float v = acc[e];
#pragma unroll
    for (int s = 32; s > 0; s >>= 1) v += __shfl_xor(v, s, 64);
    acc[e] = v + br[e];
  }

  if (lane == 0) {
    float mx = acc[0];
#pragma unroll
    for (int e = 1; e < E_; e++) mx = fmaxf(mx, acc[e]);
    float s = 0.f, ex[E_];
#pragma unroll
    for (int e = 0; e < E_; e++) { ex[e] = expf(acc[e] - mx); s += ex[e]; }
    float inv = 1.f / s;
#pragma unroll
    for (int e = 0; e < E_; e++) gate1[(size_t)token * E_ + e] = ex[e] * inv;

    int e0 = 0;
#pragma unroll
    for (int e = 1; e < E_; e++) if (acc[e] > acc[e0]) e0 = e;
    int e1 = (e0 == 0) ? 1 : 0;
#pragma unroll
    for (int e = 0; e < E_; e++) if (e != e0 && acc[e] > acc[e1]) e1 = e;
    float t2 = expf(acc[e1] - acc[e0]);
    float w0 = 1.f / (1.f + t2), w1 = t2 / (1.f + t2);
    topk_e[token * 2]     = e0; topk_e[token * 2 + 1] = e1;
    topk_w[token * 2]     = w0; topk_w[token * 2 + 1] = w1;
    atomicAdd(&counts[e0], 1); atomicAdd(&counts[e1], 1);
  }
}

// ---------------- build padded tile table (trivial) ----------------
__global__ void build_tiles_kernel(const int* __restrict__ counts, int* pbase,
                                   int* cursors, int* tile_expert, int* num_tiles)
{
  if (threadIdx.x == 0 && blockIdx.x == 0) {
    int t = 0;
    for (int e = 0; e < E_; e++) {
      pbase[e] = t * BM;
      cursors[e] = 0;
      int nt = (counts[e] + BM - 1) / BM;
      for (int i = 0; i < nt; i++) tile_expert[t++] = e;
    }
    *num_tiles = t;
  }
}

// ---------------- scatter token->padded row ----------------
__global__ __launch_bounds__(256) void scatter_kernel(
    const int* __restrict__ topk_e, const float* __restrict__ topk_w,
    const int* __restrict__ pbase, int* __restrict__ cursors,
    int* __restrict__ prow_token, float* __restrict__ prow_w)
{
  int idx = blockIdx.x * 256 + threadIdx.x;
  if (idx >= R_) return;
  int e = topk_e[idx];
  int pos = atomicAdd(&cursors[e], 1);
  int p = pbase[e] + pos;
  prow_token[p] = idx >> 1;
  prow_w[p] = topk_w[idx];
}

// ---------------- GEMM1: H = gelu(Xg @ Wfc[e] + bfc[e]) ----------------
__global__ __launch_bounds__(256) void fc_gemm_kernel(
    const float* __restrict__ x, const float* __restrict__ Wfc,
    const float* __restrict__ bfc, const int* __restrict__ prow_token,
    const int* __restrict__ tile_expert, const int* __restrict__ num_tiles_p,
    unsigned short* __restrict__ H)
{
  const int tile = blockIdx.y;
  if (tile >= *num_tiles_p) return;
  const int e  = tile_expert[tile];
  const int n0 = blockIdx.x * BN;

  __shared__ unsigned short As[BM * BK];   // [row][k]
  __shared__ unsigned short Bs[BN * BK];   // [col][k] (transposed for b128 frag reads)
  __shared__ int toks[BM];

  const int t = threadIdx.x;
  if (t < BM) toks[t] = prow_token[tile * BM + t];
  __syncthreads();

  const int lane = t & 63, wid = t >> 6;
  const int wm = (wid >> 1) * 64, wn = (wid & 1) * 64;
  const int lrow = lane & 15, quad = lane >> 4;

  floatx4 acc[4][4];
#pragma unroll
  for (int i = 0; i < 4; i++)
#pragma unroll
    for (int j = 0; j < 4; j++) acc[i][j] = (floatx4){0.f, 0.f, 0.f, 0.f};

  const int arow = t >> 1;
  const int akh  = (t & 1) * 16;
  const int bn8  = (t & 15) * 8;
  const int bk2  = (t >> 4) * 2;

  const float* Wb = Wfc + (size_t)e * ((size_t)D_ * H_);
  const int atok = toks[arow];
  const float* aptr = (atok >= 0) ? (x + (size_t)atok * D_ + akh) : nullptr;

  for (int k0 = 0; k0 < D_; k0 += BK) {
    // --- stage A (gathered f32 -> bf16) ---
    {
      float av[16];
      if (aptr) {
        const float4* s = (const float4*)(aptr + k0);
        float4 f0 = s[0], f1 = s[1], f2 = s[2], f3 = s[3];
        av[0]=f0.x; av[1]=f0.y; av[2]=f0.z;  av[3]=f0.w;
        av[4]=f1.x; av[5]=f1.y; av[6]=f1.z;  av[7]=f1.w;
        av[8]=f2.x; av[9]=f2.y; av[10]=f2.z; av[11]=f2.w;
        av[12]=f3.x;av[13]=f3.y;av[14]=f3.z; av[15]=f3.w;
      } else {
#pragma unroll
        for (int i = 0; i < 16; i++) av[i] = 0.f;
      }
      unsigned short tmp[16];
#pragma unroll
      for (int i = 0; i < 16; i++) tmp[i] = f2bf(av[i]);
      unsigned short* dst = &As[arow * BK + akh];
      *(short8*)dst       = *(short8*)tmp;
      *(short8*)(dst + 8) = *(short8*)(tmp + 8);
    }
    // --- stage B (f32 -> bf16, transposed into [n][k]) ---
    {
      const float* r0 = Wb + (size_t)(k0 + bk2) * H_ + n0 + bn8;
      const float* r1 = r0 + H_;
      float4 a0 = ((const float4*)r0)[0], a1 = ((const float4*)r0)[1];
      float4 b0 = ((const float4*)r1)[0], b1 = ((const float4*)r1)[1];
      float av0[8] = {a0.x,a0.y,a0.z,a0.w,a1.x,a1.y,a1.z,a1.w};
      float bv0[8] = {b0.x,b0.y,b0.z,b0.w,b1.x,b1.y,b1.z,b1.w};
#pragma unroll
      for (int j = 0; j < 8; j++) {
        ushort2 u; u.x = f2bf(av0[j]); u.y = f2bf(bv0[j]);
        *(ushort2*)&Bs[(bn8 + j) * BK + bk2] = u;
      }
    }
    __syncthreads();

    short8 af[4], bfr[4];
#pragma unroll
    for (int mi = 0; mi < 4; mi++)
      af[mi]  = *(const short8*)&As[(wm + mi * 16 + lrow) * BK + quad * 8];
#pragma unroll
    for (int ni = 0; ni < 4; ni++)
      bfr[ni] = *(const short8*)&Bs[(wn + ni * 16 + lrow) * BK + quad * 8];
#pragma unroll
    for (int mi = 0; mi < 4; mi++)
#pragma unroll
      for (int ni = 0; ni < 4; ni++)
        acc[mi][ni] = __builtin_amdgcn_mfma_f32_16x16x32_bf16(af[mi], bfr[ni], acc[mi][ni], 0, 0, 0);
    __syncthreads();
  }

  // --- epilogue: bias + gelu -> H (bf16) ---
  const float* bias = bfc + (size_t)e * H_ + n0;
#pragma unroll
  for (int mi = 0; mi < 4; mi++) {
    int row = wm + mi * 16 + quad * 4;
#pragma unroll
    for (int ni = 0; ni < 4; ni++) {
      int col = wn + ni * 16 + lrow;
      float b = bias[col];
#pragma unroll
      for (int r = 0; r < 4; r++) {
        float v = acc[mi][ni][r] + b;
        H[(size_t)(tile * BM + row + r) * H_ + n0 + col] = f2bf(gelu_tanh(v));
      }
    }
  }
}

// ---------------- GEMM2: out += w * (H @ Wproj[e] + bproj[e]) ----------------
__global__ __launch_bounds__(256) void proj_gemm_kernel(
    const unsigned short* __restrict__ H, const float* __restrict__ Wpj,
    const float* __restrict__ bpj, const int* __restrict__ prow_token,
    const float* __restrict__ prow_w, const int* __restrict__ tile_expert,
    const int* __restrict__ num_tiles_p, float* __restrict__ out)
{
  const int tile = blockIdx.y;
  if (tile >= *num_tiles_p) return;
  const int e  = tile_expert[tile];
  const int n0 = blockIdx.x * BN;

  __shared__ unsigned short As[BM * BK];
  __shared__ unsigned short Bs[BN * BK];
  __shared__ int   toks[BM];
  __shared__ float wgt[BM];

  const int t = threadIdx.x;
  if (t < BM) { toks[t] = prow_token[tile * BM + t]; wgt[t] = prow_w[tile * BM + t]; }
  __syncthreads();

  const int lane = t & 63, wid = t >> 6;
  const int wm = (wid >> 1) * 64, wn = (wid & 1) * 64;
  const int lrow = lane & 15, quad = lane >> 4;

  floatx4 acc[4][4];
#pragma unroll
  for (int i = 0; i < 4; i++)
#pragma unroll
    for (int j = 0; j < 4; j++) acc[i][j] = (floatx4){0.f, 0.f, 0.f, 0.f};

  const int arow = t >> 1;
  const int akh  = (t & 1) * 16;
  const int bn8  = (t & 15) * 8;
  const int bk2  = (t >> 4) * 2;

  const float* Wb = Wpj + (size_t)e * ((size_t)H_ * D_);
  const unsigned short* aptr = H + (size_t)(tile * BM + arow) * H_ + akh;

  for (int k0 = 0; k0 < H_; k0 += BK) {
    // --- stage A (bf16 copy) ---
    {
      const short8* s = (const short8*)(aptr + k0);
      short8 s0 = s[0], s1 = s[1];
      unsigned short* dst = &As[arow * BK + akh];
      *(short8*)dst       = s0;
      *(short8*)(dst + 8) = s1;
    }
    // --- stage B (f32 -> bf16, transposed) ---
    {
      const float* r0 = Wb + (size_t)(k0 + bk2) * D_ + n0 + bn8;
      const float* r1 = r0 + D_;
      float4 a0 = ((const float4*)r0)[0], a1 = ((const float4*)r0)[1];
      float4 b0 = ((const float4*)r1)[0], b1 = ((const float4*)r1)[1];
      float av0[8] = {a0.x,a0.y,a0.z,a0.w,a1.x,a1.y,a1.z,a1.w};
      float bv0[8] = {b0.x,b0.y,b0.z,b0.w,b1.x,b1.y,b1.z,b1.w};
#pragma unroll
      for (int j = 0; j < 8; j++) {
        ushort2 u; u.x = f2bf(av0[j]); u.y = f2bf(bv0[j]);
        *(ushort2*)&Bs[(bn8 + j) * BK + bk2] = u;
      }
    }
    __syncthreads();

    short8 af[4], bfr[4];
#pragma unroll
    for (int mi = 0; mi < 4; mi++)
      af[mi]  = *(const short8*)&As[(wm + mi * 16 + lrow) * BK + quad * 8];
#pragma unroll
    for (int ni = 0; ni < 4; ni++)
      bfr[ni] = *(const short8*)&Bs[(wn + ni * 16 + lrow) * BK + quad * 8];
#pragma unroll
    for (int mi = 0; mi < 4; mi++)
#pragma unroll
      for (int ni = 0; ni < 4; ni++)
        acc[mi][ni] = __builtin_amdgcn_mfma_f32_16x16x32_bf16(af[mi], bfr[ni], acc[mi][ni], 0, 0, 0);
    __syncthreads();
  }

  // --- epilogue: bias, gate-weight, atomic scatter-add into out ---
  const float* bias = bpj + (size_t)e * D_ + n0;
#pragma unroll
  for (int mi = 0; mi < 4; mi++) {
    int row = wm + mi * 16 + quad * 4;
#pragma unroll
    for (int ni = 0; ni < 4; ni++) {
      int col = wn + ni * 16 + lrow;
      float b = bias[col];
#pragma unroll
      for (int r = 0; r < 4; r++) {
        int rr = row + r;
        int tok = toks[rr];
        if (tok >= 0) {
          float v = (acc[mi][ni][r] + b) * wgt[rr];
          atomicAdd(&out[(size_t)tok * D_ + n0 + col], v);
        }
      }
    }
  }
}

// ---------------- host launcher ----------------
extern "C" void kernel_launch(void* const* d_in, const int* in_sizes, int n_in,
                              void* d_out, int out_size, void* d_ws, size_t ws_size,
                              hipStream_t stream)
{
  const float* x    = (const float*)d_in[0];
  const int*   cidx = (const int*)d_in[1];
  const float* dt   = (const float*)d_in[2];
  const float* dd   = (const float*)d_in[3];
  const float* drg  = (const float*)d_in[4];
  const float* de   = (const float*)d_in[5];
  const float* cemb = (const float*)d_in[6];
  const float* Wr   = (const float*)d_in[7];
  const float* br   = (const float*)d_in[8];
  const float* Wfc  = (const float*)d_in[9];
  const float* bfc  = (const float*)d_in[10];
  const float* Wpj  = (const float*)d_in[11];
  const float* bpj  = (const float*)d_in[12];

  float* out   = (float*)d_out;
  float* gate1 = out + OUT_ELEMS;

  // workspace layout (~277.4 MB total)
  char* ws = (char*)d_ws;
  size_t off = 0;
  auto take = [&](size_t bytes) { size_t r = off; off += (bytes + 255) & ~(size_t)255; return r; };
  unsigned short* Hbuf      = (unsigned short*)(ws + take((size_t)PADROWS * H_ * 2));
  int*   topk_e     = (int*)  (ws + take((size_t)R_ * 4));
  float* topk_w     = (float*)(ws + take((size_t)R_ * 4));
  int*   prow_token = (int*)  (ws + take((size_t)PADROWS * 4));
  float* prow_w     = (float*)(ws + take((size_t)PADROWS * 4));
  int*   counts     = (int*)  (ws + take(E_ * 4));
  int*   cursors    = (int*)  (ws + take(E_ * 4));
  int*   pbase      = (int*)  (ws + take(E_ * 4));
  int*   tile_expert= (int*)  (ws + take(MAXT * 4));
  int*   num_tiles  = (int*)  (ws + take(4));
  (void)ws_size; (void)in_sizes; (void)n_in; (void)out_size;

  hipMemsetAsync(d_out, 0, OUT_ELEMS * 4, stream);            // out region only; gate1 fully written
  hipMemsetAsync(counts, 0, E_ * 4, stream);
  hipMemsetAsync(prow_token, 0xFF, (size_t)PADROWS * 4, stream); // -1 sentinel for padded holes

  router_kernel<<<N_TOK / 4, 256, 0, stream>>>(x, cidx, dt, dd, drg, de, cemb, Wr, br,
                                               gate1, topk_e, topk_w, counts);
  build_tiles_kernel<<<1, 64, 0, stream>>>(counts, pbase, cursors, tile_expert, num_tiles);
  scatter_kernel<<<R_ / 256, 256, 0, stream>>>(topk_e, topk_w, pbase, cursors, prow_token, prow_w);
  fc_gemm_kernel<<<dim3(H_ / BN, MAXT), 256, 0, stream>>>(x, Wfc, bfc, prow_token, tile_expert,
                                                          num_tiles, Hbuf);
  proj_gemm_kernel<<<dim3(D_ / BN, MAXT), 256, 0, stream>>>(Hbuf, Wpj, bpj, prow_token, prow_w,
                                                            tile_expert, num_tiles, out);
}

// Round 2
// 1888.130 us; speedup vs baseline: 1.3088x; 1.3088x over previous
//
#include <hip/hip_runtime.h>
#include <hip/hip_bf16.h>
#include <math.h>

// ---------------- problem constants ----------------
#define B_       8
#define T_       2048
#define N_TOK    (B_*T_)        // 16384 tokens
#define D_       1024
#define E_       8
#define H_       4096
#define TOPK     2
#define R_       (N_TOK*TOPK)   // 32768 gathered rows
#define OUT_ELEMS ((size_t)N_TOK*D_)

// ---------------- GEMM tiling ----------------
#define BM 128
#define BN 128
#define BK 32
#define MAXT 264                 // sum_e ceil(n_e/128) <= 263; 264 safe
#define NPH 3                    // phases (Hbuf reuse to fit ws)
#define TPP 88                   // tiles per phase, 3*88 = 264
#define HROWS (TPP*BM)           // 11264 rows per phase

typedef __attribute__((ext_vector_type(8))) short short8;
typedef __attribute__((ext_vector_type(4))) float floatx4;
typedef const __attribute__((address_space(1))) void* gptr_t;
typedef __attribute__((address_space(3))) void* lptr_t;

__device__ __forceinline__ void gl16(const void* g, void* l) {
  // async global->LDS, 16B/lane; LDS dest = wave-uniform base + lane*16
  __builtin_amdgcn_global_load_lds((gptr_t)g, (lptr_t)l, 16, 0, 0);
}

__device__ __forceinline__ unsigned short f2bf(float f) {
  union { float f; unsigned int u; } v; v.f = f;
  unsigned int u = v.u;
  u += 0x7FFFu + ((u >> 16) & 1u);   // RNE
  return (unsigned short)(u >> 16);
}

__device__ __forceinline__ float gelu_tanh(float v) {
  float c = v + 0.044715f * v * v * v;
  return 0.5f * v * (1.0f + tanhf(0.7978845608028654f * c));
}

// ---------------- router: one wave per token ----------------
__global__ __launch_bounds__(256) void router_kernel(
    const float* __restrict__ x, const int* __restrict__ city_idx_p,
    const float* __restrict__ dt, const float* __restrict__ dd,
    const float* __restrict__ drg, const float* __restrict__ de,
    const float* __restrict__ cemb, const float* __restrict__ Wr,
    const float* __restrict__ br,
    float* __restrict__ gate1, int* __restrict__ topk_e,
    float* __restrict__ topk_w, int* __restrict__ counts)
{
  const int wid = threadIdx.x >> 6, lane = threadIdx.x & 63;
  const int token = blockIdx.x * 4 + wid;

  float acc[E_];
#pragma unroll
  for (int e = 0; e < E_; e++) acc[e] = 0.f;

  const float* ce = cemb + (*city_idx_p) * 32;

  auto fma_seg = [&](const float* src, int len, int base) {
    for (int i = lane; i < len; i += 64) {
      float f = src[i];
      const float* w = Wr + (size_t)(base + i) * E_;
      float4 w0 = *(const float4*)w;
      float4 w1 = *(const float4*)(w + 4);
      acc[0] += f * w0.x; acc[1] += f * w0.y; acc[2] += f * w0.z; acc[3] += f * w0.w;
      acc[4] += f * w1.x; acc[5] += f * w1.y; acc[6] += f * w1.z; acc[7] += f * w1.w;
    }
  };
  fma_seg(x  + (size_t)token * D_,  D_,  0);
  fma_seg(ce,                        32, 1024);
  fma_seg(dt + (size_t)token * 256, 256, 1056);
  fma_seg(dd + (size_t)token * 256, 256, 1312);
  fma_seg(drg+ (size_t)token * 128, 128, 1568);
  fma_seg(de + (size_t)token * 128, 128, 1696);

#pragma unroll
  for (int e = 0; e < E_; e++) {
    float v = acc[e];
#pragma unroll
    for (int s = 32; s > 0; s >>= 1) v += __shfl_xor(v, s, 64);
    acc[e] = v + br[e];
  }

  if (lane == 0) {
    float mx = acc[0];
#pragma unroll
    for (int e = 1; e < E_; e++) mx = fmaxf(mx, acc[e]);
    float s = 0.f, ex[E_];
#pragma unroll
    for (int e = 0; e < E_; e++) { ex[e] = expf(acc[e] - mx); s += ex[e]; }
    float inv = 1.f / s;
#pragma unroll
    for (int e = 0; e < E_; e++) gate1[(size_t)token * E_ + e] = ex[e] * inv;

    int e0 = 0;
#pragma unroll
    for (int e = 1; e < E_; e++) if (acc[e] > acc[e0]) e0 = e;
    int e1 = (e0 == 0) ? 1 : 0;
#pragma unroll
    for (int e = 0; e < E_; e++) if (e != e0 && acc[e] > acc[e1]) e1 = e;
    float t2 = expf(acc[e1] - acc[e0]);
    float w0 = 1.f / (1.f + t2), w1 = t2 / (1.f + t2);
    topk_e[token * 2]     = e0; topk_e[token * 2 + 1] = e1;
    topk_w[token * 2]     = w0; topk_w[token * 2 + 1] = w1;
    atomicAdd(&counts[e0], 1); atomicAdd(&counts[e1], 1);
  }
}

// ---------------- build padded tile table ----------------
__global__ void build_tiles_kernel(const int* __restrict__ counts, int* pbase,
                                   int* cursors, int* tile_expert, int* num_tiles)
{
  if (threadIdx.x == 0 && blockIdx.x == 0) {
    int t = 0;
    for (int e = 0; e < E_; e++) {
      pbase[e] = t * BM;
      cursors[e] = 0;
      int nt = (counts[e] + BM - 1) / BM;
      for (int i = 0; i < nt; i++) tile_expert[t++] = e;
    }
    *num_tiles = t;
  }
}

// ---------------- scatter token->padded row ----------------
__global__ __launch_bounds__(256) void scatter_kernel(
    const int* __restrict__ topk_e, const float* __restrict__ topk_w,
    const int* __restrict__ pbase, int* __restrict__ cursors,
    int* __restrict__ prow_token, float* __restrict__ prow_w)
{
  int idx = blockIdx.x * 256 + threadIdx.x;
  if (idx >= R_) return;
  int e = topk_e[idx];
  int pos = atomicAdd(&cursors[e], 1);
  int p = pbase[e] + pos;
  prow_token[p] = idx >> 1;
  prow_w[p] = topk_w[idx];
}

// ---------------- x f32 -> bf16 ----------------
__global__ __launch_bounds__(256) void xconv_kernel(const float* __restrict__ x,
                                                    unsigned short* __restrict__ xbf)
{
  size_t i = ((size_t)blockIdx.x * 256 + threadIdx.x) * 8;
  float4 a = ((const float4*)(x + i))[0], b = ((const float4*)(x + i))[1];
  unsigned short o[8] = {f2bf(a.x), f2bf(a.y), f2bf(a.z), f2bf(a.w),
                         f2bf(b.x), f2bf(b.y), f2bf(b.z), f2bf(b.w)};
  *(short8*)(xbf + i) = *(short8*)o;
}

// ---------------- W [e][K][N] f32  ->  Wt [e][N][K] bf16 ----------------
// grid (K/32, N/128, E), 256 threads; 32k x 128n tile per block
__global__ __launch_bounds__(256) void wtrans_kernel(
    const float* __restrict__ W, unsigned short* __restrict__ Wt, int K, int N)
{
  const int e = blockIdx.z, k0 = blockIdx.x * 32, n0 = blockIdx.y * 128;
  __shared__ unsigned short Ls[128 * 40];   // [n][k], stride 40 (16B-aligned rows)
  const int t = threadIdx.x;
  const int kr = t >> 3;            // 0..31
  const int cg = (t & 7) * 16;      // col group
  const float* src = W + ((size_t)e * K + k0 + kr) * N + n0 + cg;
  float4 f0 = ((const float4*)src)[0];
  float4 f1 = ((const float4*)src)[1];
  float4 f2 = ((const float4*)src)[2];
  float4 f3 = ((const float4*)src)[3];
  float v[16] = {f0.x,f0.y,f0.z,f0.w, f1.x,f1.y,f1.z,f1.w,
                 f2.x,f2.y,f2.z,f2.w, f3.x,f3.y,f3.z,f3.w};
#pragma unroll
  for (int j = 0; j < 16; j++) Ls[(cg + j) * 40 + kr] = f2bf(v[j]);
  __syncthreads();
  const int r = t >> 1, hh = (t & 1) * 16;
  unsigned short* dst = Wt + ((size_t)e * N + n0 + r) * K + k0 + hh;
  short8 o0 = *(short8*)&Ls[r * 40 + hh];
  short8 o1 = *(short8*)&Ls[r * 40 + hh + 8];
  *(short8*)dst       = o0;
  *(short8*)(dst + 8) = o1;
}

// ---------------- GEMM1: H = gelu(Xg @ Wfc[e] + bfc[e]) ----------------
__global__ __launch_bounds__(256) void fc_gemm_kernel(
    const unsigned short* __restrict__ xbf, const unsigned short* __restrict__ Wt,
    const float* __restrict__ bfc, const int* __restrict__ prow_token,
    const int* __restrict__ tile_expert, const int* __restrict__ num_tiles_p,
    const unsigned short* __restrict__ zrow,
    unsigned short* __restrict__ H, int tile_base)
{
  const int tile = tile_base + blockIdx.y;
  if (tile >= *num_tiles_p) return;
  const int e  = tile_expert[tile];
  const int n0 = blockIdx.x * BN;
  const int ltile = tile - tile_base;

  __shared__ unsigned short As[BM * BK];   // [row][k], stride 32, no pad (m97 layout)
  __shared__ unsigned short Bs[BN * BK];
  __shared__ int toks[BM];

  const int t = threadIdx.x;
  if (t < BM) toks[t] = prow_token[tile * BM + t];
  __syncthreads();

  const int lane = t & 63, wid = t >> 6;
  // staging: wave w covers LDS slots [w*128, w*128+128); lane l -> slot w*128 + i*64 + l
  const int ko = (lane & 3) * 8;               // k offset (shorts)
  const int r0 = wid * 32 + (lane >> 2);       // rows r0 and r0+16
  const int tk0 = toks[r0], tk1 = toks[r0 + 16];
  const unsigned short* pa0 = (tk0 >= 0) ? xbf + (size_t)tk0 * D_ + ko : zrow + ko;
  const unsigned short* pa1 = (tk1 >= 0) ? xbf + (size_t)tk1 * D_ + ko : zrow + ko;
  const unsigned short* WtE = Wt + (size_t)e * H_ * D_;
  const unsigned short* pb0 = WtE + (size_t)(n0 + r0) * D_ + ko;
  const unsigned short* pb1 = pb0 + (size_t)16 * D_;
  unsigned short* lA0 = &As[wid * 1024];
  unsigned short* lA1 = &As[wid * 1024 + 512];
  unsigned short* lB0 = &Bs[wid * 1024];
  unsigned short* lB1 = &Bs[wid * 1024 + 512];

  const int wm = (wid >> 1) * 64, wn = (wid & 1) * 64;
  const int lrow = lane & 15, quad = lane >> 4;

  floatx4 acc[4][4];
#pragma unroll
  for (int i = 0; i < 4; i++)
#pragma unroll
    for (int j = 0; j < 4; j++) acc[i][j] = (floatx4){0.f, 0.f, 0.f, 0.f};

  for (int k0 = 0; k0 < D_; k0 += BK) {
    gl16(pa0 + k0, lA0);
    gl16(pa1 + k0, lA1);
    gl16(pb0 + k0, lB0);
    gl16(pb1 + k0, lB1);
    __syncthreads();   // drains vmcnt -> LDS tile ready

    short8 af[4], bfr[4];
#pragma unroll
    for (int mi = 0; mi < 4; mi++)
      af[mi]  = *(const short8*)&As[(wm + mi * 16 + lrow) * BK + quad * 8];
#pragma unroll
    for (int ni = 0; ni < 4; ni++)
      bfr[ni] = *(const short8*)&Bs[(wn + ni * 16 + lrow) * BK + quad * 8];
#pragma unroll
    for (int mi = 0; mi < 4; mi++)
#pragma unroll
      for (int ni = 0; ni < 4; ni++)
        acc[mi][ni] = __builtin_amdgcn_mfma_f32_16x16x32_bf16(af[mi], bfr[ni], acc[mi][ni], 0, 0, 0);
    __syncthreads();
  }

  const float* bias = bfc + (size_t)e * H_ + n0;
#pragma unroll
  for (int mi = 0; mi < 4; mi++) {
    int row = wm + mi * 16 + quad * 4;
#pragma unroll
    for (int ni = 0; ni < 4; ni++) {
      int col = wn + ni * 16 + lrow;
      float b = bias[col];
#pragma unroll
      for (int r = 0; r < 4; r++) {
        float v = acc[mi][ni][r] + b;
        H[(size_t)(ltile * BM + row + r) * H_ + n0 + col] = f2bf(gelu_tanh(v));
      }
    }
  }
}

// ---------------- GEMM2: out += w * (H @ Wproj[e] + bproj[e]) ----------------
__global__ __launch_bounds__(256) void proj_gemm_kernel(
    const unsigned short* __restrict__ H, const unsigned short* __restrict__ Wt,
    const float* __restrict__ bpj, const int* __restrict__ prow_token,
    const float* __restrict__ prow_w, const int* __restrict__ tile_expert,
    const int* __restrict__ num_tiles_p, float* __restrict__ out, int tile_base)
{
  const int tile = tile_base + blockIdx.y;
  if (tile >= *num_tiles_p) return;
  const int e  = tile_expert[tile];
  const int n0 = blockIdx.x * BN;
  const int ltile = tile - tile_base;

  __shared__ unsigned short As[BM * BK];
  __shared__ unsigned short Bs[BN * BK];
  __shared__ int   toks[BM];
  __shared__ float wgt[BM];

  const int t = threadIdx.x;
  if (t < BM) { toks[t] = prow_token[tile * BM + t]; wgt[t] = prow_w[tile * BM + t]; }
  __syncthreads();

  const int lane = t & 63, wid = t >> 6;
  const int ko = (lane & 3) * 8;
  const int r0 = wid * 32 + (lane >> 2);
  const unsigned short* pa0 = H + (size_t)(ltile * BM + r0) * H_ + ko;
  const unsigned short* pa1 = pa0 + (size_t)16 * H_;
  const unsigned short* WtE = Wt + (size_t)e * D_ * H_;
  const unsigned short* pb0 = WtE + (size_t)(n0 + r0) * H_ + ko;
  const unsigned short* pb1 = pb0 + (size_t)16 * H_;
  unsigned short* lA0 = &As[wid * 1024];
  unsigned short* lA1 = &As[wid * 1024 + 512];
  unsigned short* lB0 = &Bs[wid * 1024];
  unsigned short* lB1 = &Bs[wid * 1024 + 512];

  const int wm = (wid >> 1) * 64, wn = (wid & 1) * 64;
  const int lrow = lane & 15, quad = lane >> 4;

  floatx4 acc[4][4];
#pragma unroll
  for (int i = 0; i < 4; i++)
#pragma unroll
    for (int j = 0; j < 4; j++) acc[i][j] = (floatx4){0.f, 0.f, 0.f, 0.f};

  for (int k0 = 0; k0 < H_; k0 += BK) {
    gl16(pa0 + k0, lA0);
    gl16(pa1 + k0, lA1);
    gl16(pb0 + k0, lB0);
    gl16(pb1 + k0, lB1);
    __syncthreads();

    short8 af[4], bfr[4];
#pragma unroll
    for (int mi = 0; mi < 4; mi++)
      af[mi]  = *(const short8*)&As[(wm + mi * 16 + lrow) * BK + quad * 8];
#pragma unroll
    for (int ni = 0; ni < 4; ni++)
      bfr[ni] = *(const short8*)&Bs[(wn + ni * 16 + lrow) * BK + quad * 8];
#pragma unroll
    for (int mi = 0; mi < 4; mi++)
#pragma unroll
      for (int ni = 0; ni < 4; ni++)
        acc[mi][ni] = __builtin_amdgcn_mfma_f32_16x16x32_bf16(af[mi], bfr[ni], acc[mi][ni], 0, 0, 0);
    __syncthreads();
  }

  const float* bias = bpj + (size_t)e * D_ + n0;
#pragma unroll
  for (int mi = 0; mi < 4; mi++) {
    int row = wm + mi * 16 + quad * 4;
#pragma unroll
    for (int ni = 0; ni < 4; ni++) {
      int col = wn + ni * 16 + lrow;
      float b = bias[col];
#pragma unroll
      for (int r = 0; r < 4; r++) {
        int rr = row + r;
        int tok = toks[rr];
        if (tok >= 0) {
          float v = (acc[mi][ni][r] + b) * wgt[rr];
          atomicAdd(&out[(size_t)tok * D_ + n0 + col], v);
        }
      }
    }
  }
}

// ---------------- host launcher ----------------
extern "C" void kernel_launch(void* const* d_in, const int* in_sizes, int n_in,
                              void* d_out, int out_size, void* d_ws, size_t ws_size,
                              hipStream_t stream)
{
  const float* x    = (const float*)d_in[0];
  const int*   cidx = (const int*)d_in[1];
  const float* dt   = (const float*)d_in[2];
  const float* dd   = (const float*)d_in[3];
  const float* drg  = (const float*)d_in[4];
  const float* de   = (const float*)d_in[5];
  const float* cemb = (const float*)d_in[6];
  const float* Wr   = (const float*)d_in[7];
  const float* br   = (const float*)d_in[8];
  const float* Wfc  = (const float*)d_in[9];
  const float* bfc  = (const float*)d_in[10];
  const float* Wpj  = (const float*)d_in[11];
  const float* bpj  = (const float*)d_in[12];

  float* out   = (float*)d_out;
  float* gate1 = out + OUT_ELEMS;

  // workspace layout (~261 MB; round-1 proved ws >= 278 MB)
  char* ws = (char*)d_ws;
  size_t off = 0;
  auto take = [&](size_t bytes) { size_t r = off; off += (bytes + 255) & ~(size_t)255; return r; };
  unsigned short* Hbuf  = (unsigned short*)(ws + take((size_t)HROWS * H_ * 2));   // 92.3 MB
  unsigned short* xbf   = (unsigned short*)(ws + take((size_t)N_TOK * D_ * 2));   // 33.6 MB
  unsigned short* WtFc  = (unsigned short*)(ws + take((size_t)E_ * H_ * D_ * 2)); // 67.1 MB
  unsigned short* WtPj  = (unsigned short*)(ws + take((size_t)E_ * D_ * H_ * 2)); // 67.1 MB
  int*   topk_e      = (int*)  (ws + take((size_t)R_ * 4));
  float* topk_w      = (float*)(ws + take((size_t)R_ * 4));
  int*   prow_token  = (int*)  (ws + take((size_t)(MAXT * BM) * 4));
  float* prow_w      = (float*)(ws + take((size_t)(MAXT * BM) * 4));
  unsigned short* zrow = (unsigned short*)(ws + take(4096));
  int*   counts      = (int*)  (ws + take(E_ * 4));
  int*   cursors     = (int*)  (ws + take(E_ * 4));
  int*   pbase       = (int*)  (ws + take(E_ * 4));
  int*   tile_expert = (int*)  (ws + take(MAXT * 4));
  int*   num_tiles   = (int*)  (ws + take(4));
  (void)ws_size; (void)in_sizes; (void)n_in; (void)out_size;

  hipMemsetAsync(d_out, 0, OUT_ELEMS * 4, stream);
  hipMemsetAsync(counts, 0, E_ * 4, stream);
  hipMemsetAsync(prow_token, 0xFF, (size_t)(MAXT * BM) * 4, stream);
  hipMemsetAsync(zrow, 0, 4096, stream);

  // one-time (per launch) conversions
  xconv_kernel<<<(N_TOK * D_) / (256 * 8), 256, 0, stream>>>(x, xbf);
  wtrans_kernel<<<dim3(D_ / 32, H_ / 128, E_), 256, 0, stream>>>(Wfc, WtFc, D_, H_); // K=D,N=H
  wtrans_kernel<<<dim3(H_ / 32, D_ / 128, E_), 256, 0, stream>>>(Wpj, WtPj, H_, D_); // K=H,N=D

  router_kernel<<<N_TOK / 4, 256, 0, stream>>>(x, cidx, dt, dd, drg, de, cemb, Wr, br,
                                               gate1, topk_e, topk_w, counts);
  build_tiles_kernel<<<1, 64, 0, stream>>>(counts, pbase, cursors, tile_expert, num_tiles);
  scatter_kernel<<<R_ / 256, 256, 0, stream>>>(topk_e, topk_w, pbase, cursors, prow_token, prow_w);

  for (int p = 0; p < NPH; p++) {
    int base = p * TPP;
    fc_gemm_kernel<<<dim3(H_ / BN, TPP), 256, 0, stream>>>(xbf, WtFc, bfc, prow_token,
                                                           tile_expert, num_tiles, zrow,
                                                           Hbuf, base);
    proj_gemm_kernel<<<dim3(D_ / BN, TPP), 256, 0, stream>>>(Hbuf, WtPj, bpj, prow_token,
                                                             prow_w, tile_expert, num_tiles,
                                                             out, base);
  }
}

// Round 3
// 1519.977 us; speedup vs baseline: 1.6258x; 1.2422x over previous
//
#include <hip/hip_runtime.h>
#include <hip/hip_bf16.h>
#include <math.h>

// ---------------- problem constants ----------------
#define B_       8
#define T_       2048
#define N_TOK    (B_*T_)        // 16384 tokens
#define D_       1024
#define E_       8
#define H_       4096
#define TOPK     2
#define R_       (N_TOK*TOPK)   // 32768 gathered rows
#define OUT_ELEMS ((size_t)N_TOK*D_)

// ---------------- GEMM tiling ----------------
#define BM 128
#define BN 128
#define BK 32
#define MAXT 264                 // sum_e ceil(n_e/128) <= 263; 264 safe
#define NPH 3                    // phases (Hbuf reuse to fit ws)
#define TPP 88                   // tiles per phase, 3*88 = 264
#define HROWS (TPP*BM)           // 11264 rows per phase

typedef __attribute__((ext_vector_type(8))) short short8;
typedef __attribute__((ext_vector_type(4))) float floatx4;
typedef const __attribute__((address_space(1))) void* gptr_t;
typedef __attribute__((address_space(3))) void* lptr_t;

__device__ __forceinline__ void gl16(const void* g, void* l) {
  // async global->LDS, 16B/lane; LDS dest = wave-uniform base + lane*16
  __builtin_amdgcn_global_load_lds((gptr_t)g, (lptr_t)l, 16, 0, 0);
}

__device__ __forceinline__ unsigned short f2bf(float f) {
  union { float f; unsigned int u; } v; v.f = f;
  unsigned int u = v.u;
  u += 0x7FFFu + ((u >> 16) & 1u);   // RNE
  return (unsigned short)(u >> 16);
}

__device__ __forceinline__ float gelu_tanh(float v) {
  float c = v + 0.044715f * v * v * v;
  return 0.5f * v * (1.0f + tanhf(0.7978845608028654f * c));
}

// ---------------- router: one wave per token (NO global atomics) ----------------
__global__ __launch_bounds__(256) void router_kernel(
    const float* __restrict__ x, const int* __restrict__ city_idx_p,
    const float* __restrict__ dt, const float* __restrict__ dd,
    const float* __restrict__ drg, const float* __restrict__ de,
    const float* __restrict__ cemb, const float* __restrict__ Wr,
    const float* __restrict__ br,
    float* __restrict__ gate1, int* __restrict__ topk_e,
    float* __restrict__ topk_w)
{
  const int wid = threadIdx.x >> 6, lane = threadIdx.x & 63;
  const int token = blockIdx.x * 4 + wid;

  float acc[E_];
#pragma unroll
  for (int e = 0; e < E_; e++) acc[e] = 0.f;

  const float* ce = cemb + (*city_idx_p) * 32;

  // ng = number of float4 groups; lane handles groups lane, lane+64, ...
  auto fma_seg4 = [&](const float* src, int ng, int base) {
    for (int i = lane; i < ng; i += 64) {
      float4 f = ((const float4*)src)[i];
      const float4* wv = (const float4*)(Wr + (size_t)(base + i * 4) * E_);
      float4 w0 = wv[0], w1 = wv[1], w2 = wv[2], w3 = wv[3];
      float4 w4 = wv[4], w5 = wv[5], w6 = wv[6], w7 = wv[7];
      acc[0] += f.x * w0.x; acc[1] += f.x * w0.y; acc[2] += f.x * w0.z; acc[3] += f.x * w0.w;
      acc[4] += f.x * w1.x; acc[5] += f.x * w1.y; acc[6] += f.x * w1.z; acc[7] += f.x * w1.w;
      acc[0] += f.y * w2.x; acc[1] += f.y * w2.y; acc[2] += f.y * w2.z; acc[3] += f.y * w2.w;
      acc[4] += f.y * w3.x; acc[5] += f.y * w3.y; acc[6] += f.y * w3.z; acc[7] += f.y * w3.w;
      acc[0] += f.z * w4.x; acc[1] += f.z * w4.y; acc[2] += f.z * w4.z; acc[3] += f.z * w4.w;
      acc[4] += f.z * w5.x; acc[5] += f.z * w5.y; acc[6] += f.z * w5.z; acc[7] += f.z * w5.w;
      acc[0] += f.w * w6.x; acc[1] += f.w * w6.y; acc[2] += f.w * w6.z; acc[3] += f.w * w6.w;
      acc[4] += f.w * w7.x; acc[5] += f.w * w7.y; acc[6] += f.w * w7.z; acc[7] += f.w * w7.w;
    }
  };
  fma_seg4(x  + (size_t)token * D_,  D_ / 4, 0);
  fma_seg4(ce,                       32 / 4, 1024);
  fma_seg4(dt + (size_t)token * 256, 256 / 4, 1056);
  fma_seg4(dd + (size_t)token * 256, 256 / 4, 1312);
  fma_seg4(drg+ (size_t)token * 128, 128 / 4, 1568);
  fma_seg4(de + (size_t)token * 128, 128 / 4, 1696);

#pragma unroll
  for (int e = 0; e < E_; e++) {
    float v = acc[e];
#pragma unroll
    for (int s = 32; s > 0; s >>= 1) v += __shfl_xor(v, s, 64);
    acc[e] = v + br[e];
  }

  if (lane == 0) {
    float mx = acc[0];
#pragma unroll
    for (int e = 1; e < E_; e++) mx = fmaxf(mx, acc[e]);
    float s = 0.f, ex[E_];
#pragma unroll
    for (int e = 0; e < E_; e++) { ex[e] = expf(acc[e] - mx); s += ex[e]; }
    float inv = 1.f / s;
#pragma unroll
    for (int e = 0; e < E_; e++) gate1[(size_t)token * E_ + e] = ex[e] * inv;

    int e0 = 0;
#pragma unroll
    for (int e = 1; e < E_; e++) if (acc[e] > acc[e0]) e0 = e;
    int e1 = (e0 == 0) ? 1 : 0;
#pragma unroll
    for (int e = 0; e < E_; e++) if (e != e0 && acc[e] > acc[e1]) e1 = e;
    float t2 = expf(acc[e1] - acc[e0]);
    float w0 = 1.f / (1.f + t2), w1 = t2 / (1.f + t2);
    topk_e[token * 2]     = e0; topk_e[token * 2 + 1] = e1;
    topk_w[token * 2]     = w0; topk_w[token * 2 + 1] = w1;
  }
}

// ---------------- histogram: LDS bins, 8 global atomics per block ----------------
__global__ __launch_bounds__(256) void hist_kernel(const int* __restrict__ topk_e,
                                                   int* __restrict__ counts)
{
  __shared__ int h[E_];
  const int t = threadIdx.x;
  if (t < E_) h[t] = 0;
  __syncthreads();
  const int base = blockIdx.x * 1024 + t;
#pragma unroll
  for (int j = 0; j < 4; j++) atomicAdd(&h[topk_e[base + j * 256]], 1);
  __syncthreads();
  if (t < E_ && h[t] > 0) atomicAdd(&counts[t], h[t]);
}

// ---------------- build padded tile table ----------------
__global__ void build_tiles_kernel(const int* __restrict__ counts, int* pbase,
                                   int* cursors, int* tile_expert, int* num_tiles)
{
  if (threadIdx.x == 0 && blockIdx.x == 0) {
    int t = 0;
    for (int e = 0; e < E_; e++) {
      pbase[e] = t * BM;
      cursors[e] = 0;
      int nt = (counts[e] + BM - 1) / BM;
      for (int i = 0; i < nt; i++) tile_expert[t++] = e;
    }
    *num_tiles = t;
  }
}

// ---------------- scatter token->padded row (hierarchical reservation) ----------------
__global__ __launch_bounds__(256) void scatter_kernel(
    const int* __restrict__ topk_e, const float* __restrict__ topk_w,
    const int* __restrict__ pbase, int* __restrict__ cursors,
    int* __restrict__ prow_token, float* __restrict__ prow_w)
{
  __shared__ int wcnt[4][E_];
  __shared__ int wbase[4][E_];
  const int t = threadIdx.x, lane = t & 63, wid = t >> 6;
  if (t < 32) ((int*)wcnt)[t] = 0;
  __syncthreads();

  const int idx = blockIdx.x * 256 + t;
  const int e = topk_e[idx];
  const float w = topk_w[idx];

  // same-e lane mask via 3 ballots (e has 3 bits)
  unsigned long long b0 = __ballot(e & 1);
  unsigned long long b1 = __ballot(e & 2);
  unsigned long long b2 = __ballot(e & 4);
  unsigned long long m = ((e & 1) ? b0 : ~b0) & ((e & 2) ? b1 : ~b1) & ((e & 4) ? b2 : ~b2);
  unsigned long long below = ((unsigned long long)1 << lane) - 1;
  const int rank = __popcll(m & below);
  if (rank == 0) wcnt[wid][e] = __popcll(m);
  __syncthreads();

  if (t < E_) {
    int run = 0, tmp[4];
#pragma unroll
    for (int w2 = 0; w2 < 4; w2++) { tmp[w2] = run; run += wcnt[w2][t]; }
    int gb = (run > 0) ? atomicAdd(&cursors[t], run) : 0;
#pragma unroll
    for (int w2 = 0; w2 < 4; w2++) wbase[w2][t] = gb + tmp[w2];
  }
  __syncthreads();

  const int pos = pbase[e] + wbase[wid][e] + rank;
  prow_token[pos] = idx >> 1;
  prow_w[pos] = w;
}

// ---------------- x f32 -> bf16 ----------------
__global__ __launch_bounds__(256) void xconv_kernel(const float* __restrict__ x,
                                                    unsigned short* __restrict__ xbf)
{
  size_t i = ((size_t)blockIdx.x * 256 + threadIdx.x) * 8;
  float4 a = ((const float4*)(x + i))[0], b = ((const float4*)(x + i))[1];
  unsigned short o[8] = {f2bf(a.x), f2bf(a.y), f2bf(a.z), f2bf(a.w),
                         f2bf(b.x), f2bf(b.y), f2bf(b.z), f2bf(b.w)};
  *(short8*)(xbf + i) = *(short8*)o;
}

// ---------------- W [e][K][N] f32  ->  Wt [e][N][K] bf16 ----------------
__global__ __launch_bounds__(256) void wtrans_kernel(
    const float* __restrict__ W, unsigned short* __restrict__ Wt, int K, int N)
{
  const int e = blockIdx.z, k0 = blockIdx.x * 32, n0 = blockIdx.y * 128;
  __shared__ unsigned short Ls[128 * 40];   // [n][k], stride 40
  const int t = threadIdx.x;
  const int kr = t >> 3;
  const int cg = (t & 7) * 16;
  const float* src = W + ((size_t)e * K + k0 + kr) * N + n0 + cg;
  float4 f0 = ((const float4*)src)[0];
  float4 f1 = ((const float4*)src)[1];
  float4 f2 = ((const float4*)src)[2];
  float4 f3 = ((const float4*)src)[3];
  float v[16] = {f0.x,f0.y,f0.z,f0.w, f1.x,f1.y,f1.z,f1.w,
                 f2.x,f2.y,f2.z,f2.w, f3.x,f3.y,f3.z,f3.w};
#pragma unroll
  for (int j = 0; j < 16; j++) Ls[(cg + j) * 40 + kr] = f2bf(v[j]);
  __syncthreads();
  const int r = t >> 1, hh = (t & 1) * 16;
  unsigned short* dst = Wt + ((size_t)e * N + n0 + r) * K + k0 + hh;
  short8 o0 = *(short8*)&Ls[r * 40 + hh];
  short8 o1 = *(short8*)&Ls[r * 40 + hh + 8];
  *(short8*)dst       = o0;
  *(short8*)(dst + 8) = o1;
}

// ---------------- GEMM1: H = gelu(Xg @ Wfc[e] + bfc[e]) ----------------
__global__ __launch_bounds__(256) void fc_gemm_kernel(
    const unsigned short* __restrict__ xbf, const unsigned short* __restrict__ Wt,
    const float* __restrict__ bfc, const int* __restrict__ prow_token,
    const int* __restrict__ tile_expert, const int* __restrict__ num_tiles_p,
    const unsigned short* __restrict__ zrow,
    unsigned short* __restrict__ H, int tile_base)
{
  const int tile = tile_base + blockIdx.y;
  if (tile >= *num_tiles_p) return;
  const int e  = tile_expert[tile];
  const int n0 = blockIdx.x * BN;
  const int ltile = tile - tile_base;

  __shared__ unsigned short As[BM * BK];   // [row][k], stride 32 (m97 layout)
  __shared__ unsigned short Bs[BN * BK];
  __shared__ int toks[BM];

  const int t = threadIdx.x;
  if (t < BM) toks[t] = prow_token[tile * BM + t];
  __syncthreads();

  const int lane = t & 63, wid = t >> 6;
  const int ko = (lane & 3) * 8;
  const int r0 = wid * 32 + (lane >> 2);
  const int tk0 = toks[r0], tk1 = toks[r0 + 16];
  const unsigned short* pa0 = (tk0 >= 0) ? xbf + (size_t)tk0 * D_ + ko : zrow + ko;
  const unsigned short* pa1 = (tk1 >= 0) ? xbf + (size_t)tk1 * D_ + ko : zrow + ko;
  const unsigned short* WtE = Wt + (size_t)e * H_ * D_;
  const unsigned short* pb0 = WtE + (size_t)(n0 + r0) * D_ + ko;
  const unsigned short* pb1 = pb0 + (size_t)16 * D_;
  unsigned short* lA0 = &As[wid * 1024];
  unsigned short* lA1 = &As[wid * 1024 + 512];
  unsigned short* lB0 = &Bs[wid * 1024];
  unsigned short* lB1 = &Bs[wid * 1024 + 512];

  const int wm = (wid >> 1) * 64, wn = (wid & 1) * 64;
  const int lrow = lane & 15, quad = lane >> 4;

  floatx4 acc[4][4];
#pragma unroll
  for (int i = 0; i < 4; i++)
#pragma unroll
    for (int j = 0; j < 4; j++) acc[i][j] = (floatx4){0.f, 0.f, 0.f, 0.f};

  for (int k0 = 0; k0 < D_; k0 += BK) {
    gl16(pa0 + k0, lA0);
    gl16(pa1 + k0, lA1);
    gl16(pb0 + k0, lB0);
    gl16(pb1 + k0, lB1);
    __syncthreads();

    short8 af[4], bfr[4];
#pragma unroll
    for (int mi = 0; mi < 4; mi++)
      af[mi]  = *(const short8*)&As[(wm + mi * 16 + lrow) * BK + quad * 8];
#pragma unroll
    for (int ni = 0; ni < 4; ni++)
      bfr[ni] = *(const short8*)&Bs[(wn + ni * 16 + lrow) * BK + quad * 8];
#pragma unroll
    for (int mi = 0; mi < 4; mi++)
#pragma unroll
      for (int ni = 0; ni < 4; ni++)
        acc[mi][ni] = __builtin_amdgcn_mfma_f32_16x16x32_bf16(af[mi], bfr[ni], acc[mi][ni], 0, 0, 0);
    __syncthreads();
  }

  const float* bias = bfc + (size_t)e * H_ + n0;
#pragma unroll
  for (int mi = 0; mi < 4; mi++) {
    int row = wm + mi * 16 + quad * 4;
#pragma unroll
    for (int ni = 0; ni < 4; ni++) {
      int col = wn + ni * 16 + lrow;
      float b = bias[col];
#pragma unroll
      for (int r = 0; r < 4; r++) {
        float v = acc[mi][ni][r] + b;
        H[(size_t)(ltile * BM + row + r) * H_ + n0 + col] = f2bf(gelu_tanh(v));
      }
    }
  }
}

// ---------------- GEMM2: out += w * (H @ Wproj[e] + bproj[e]) ----------------
__global__ __launch_bounds__(256) void proj_gemm_kernel(
    const unsigned short* __restrict__ H, const unsigned short* __restrict__ Wt,
    const float* __restrict__ bpj, const int* __restrict__ prow_token,
    const float* __restrict__ prow_w, const int* __restrict__ tile_expert,
    const int* __restrict__ num_tiles_p, float* __restrict__ out, int tile_base)
{
  const int tile = tile_base + blockIdx.y;
  if (tile >= *num_tiles_p) return;
  const int e  = tile_expert[tile];
  const int n0 = blockIdx.x * BN;
  const int ltile = tile - tile_base;

  __shared__ unsigned short As[BM * BK];
  __shared__ unsigned short Bs[BN * BK];
  __shared__ int   toks[BM];
  __shared__ float wgt[BM];

  const int t = threadIdx.x;
  if (t < BM) { toks[t] = prow_token[tile * BM + t]; wgt[t] = prow_w[tile * BM + t]; }
  __syncthreads();

  const int lane = t & 63, wid = t >> 6;
  const int ko = (lane & 3) * 8;
  const int r0 = wid * 32 + (lane >> 2);
  const unsigned short* pa0 = H + (size_t)(ltile * BM + r0) * H_ + ko;
  const unsigned short* pa1 = pa0 + (size_t)16 * H_;
  const unsigned short* WtE = Wt + (size_t)e * D_ * H_;
  const unsigned short* pb0 = WtE + (size_t)(n0 + r0) * H_ + ko;
  const unsigned short* pb1 = pb0 + (size_t)16 * H_;
  unsigned short* lA0 = &As[wid * 1024];
  unsigned short* lA1 = &As[wid * 1024 + 512];
  unsigned short* lB0 = &Bs[wid * 1024];
  unsigned short* lB1 = &Bs[wid * 1024 + 512];

  const int wm = (wid >> 1) * 64, wn = (wid & 1) * 64;
  const int lrow = lane & 15, quad = lane >> 4;

  floatx4 acc[4][4];
#pragma unroll
  for (int i = 0; i < 4; i++)
#pragma unroll
    for (int j = 0; j < 4; j++) acc[i][j] = (floatx4){0.f, 0.f, 0.f, 0.f};

  for (int k0 = 0; k0 < H_; k0 += BK) {
    gl16(pa0 + k0, lA0);
    gl16(pa1 + k0, lA1);
    gl16(pb0 + k0, lB0);
    gl16(pb1 + k0, lB1);
    __syncthreads();

    short8 af[4], bfr[4];
#pragma unroll
    for (int mi = 0; mi < 4; mi++)
      af[mi]  = *(const short8*)&As[(wm + mi * 16 + lrow) * BK + quad * 8];
#pragma unroll
    for (int ni = 0; ni < 4; ni++)
      bfr[ni] = *(const short8*)&Bs[(wn + ni * 16 + lrow) * BK + quad * 8];
#pragma unroll
    for (int mi = 0; mi < 4; mi++)
#pragma unroll
      for (int ni = 0; ni < 4; ni++)
        acc[mi][ni] = __builtin_amdgcn_mfma_f32_16x16x32_bf16(af[mi], bfr[ni], acc[mi][ni], 0, 0, 0);
    __syncthreads();
  }

  const float* bias = bpj + (size_t)e * D_ + n0;
#pragma unroll
  for (int mi = 0; mi < 4; mi++) {
    int row = wm + mi * 16 + quad * 4;
#pragma unroll
    for (int ni = 0; ni < 4; ni++) {
      int col = wn + ni * 16 + lrow;
      float b = bias[col];
#pragma unroll
      for (int r = 0; r < 4; r++) {
        int rr = row + r;
        int tok = toks[rr];
        if (tok >= 0) {
          float v = (acc[mi][ni][r] + b) * wgt[rr];
          atomicAdd(&out[(size_t)tok * D_ + n0 + col], v);
        }
      }
    }
  }
}

// ---------------- host launcher ----------------
extern "C" void kernel_launch(void* const* d_in, const int* in_sizes, int n_in,
                              void* d_out, int out_size, void* d_ws, size_t ws_size,
                              hipStream_t stream)
{
  const float* x    = (const float*)d_in[0];
  const int*   cidx = (const int*)d_in[1];
  const float* dt   = (const float*)d_in[2];
  const float* dd   = (const float*)d_in[3];
  const float* drg  = (const float*)d_in[4];
  const float* de   = (const float*)d_in[5];
  const float* cemb = (const float*)d_in[6];
  const float* Wr   = (const float*)d_in[7];
  const float* br   = (const float*)d_in[8];
  const float* Wfc  = (const float*)d_in[9];
  const float* bfc  = (const float*)d_in[10];
  const float* Wpj  = (const float*)d_in[11];
  const float* bpj  = (const float*)d_in[12];

  float* out   = (float*)d_out;
  float* gate1 = out + OUT_ELEMS;

  char* ws = (char*)d_ws;
  size_t off = 0;
  auto take = [&](size_t bytes) { size_t r = off; off += (bytes + 255) & ~(size_t)255; return r; };
  unsigned short* Hbuf  = (unsigned short*)(ws + take((size_t)HROWS * H_ * 2));   // 92.3 MB
  unsigned short* xbf   = (unsigned short*)(ws + take((size_t)N_TOK * D_ * 2));   // 33.6 MB
  unsigned short* WtFc  = (unsigned short*)(ws + take((size_t)E_ * H_ * D_ * 2)); // 67.1 MB
  unsigned short* WtPj  = (unsigned short*)(ws + take((size_t)E_ * D_ * H_ * 2)); // 67.1 MB
  int*   topk_e      = (int*)  (ws + take((size_t)R_ * 4));
  float* topk_w      = (float*)(ws + take((size_t)R_ * 4));
  int*   prow_token  = (int*)  (ws + take((size_t)(MAXT * BM) * 4));
  float* prow_w      = (float*)(ws + take((size_t)(MAXT * BM) * 4));
  unsigned short* zrow = (unsigned short*)(ws + take(4096));
  int*   counts      = (int*)  (ws + take(E_ * 4));
  int*   cursors     = (int*)  (ws + take(E_ * 4));
  int*   pbase       = (int*)  (ws + take(E_ * 4));
  int*   tile_expert = (int*)  (ws + take(MAXT * 4));
  int*   num_tiles   = (int*)  (ws + take(4));
  (void)ws_size; (void)in_sizes; (void)n_in; (void)out_size;

  hipMemsetAsync(d_out, 0, OUT_ELEMS * 4, stream);
  hipMemsetAsync(counts, 0, E_ * 4, stream);
  hipMemsetAsync(prow_token, 0xFF, (size_t)(MAXT * BM) * 4, stream);
  hipMemsetAsync(zrow, 0, 4096, stream);

  xconv_kernel<<<(N_TOK * D_) / (256 * 8), 256, 0, stream>>>(x, xbf);
  wtrans_kernel<<<dim3(D_ / 32, H_ / 128, E_), 256, 0, stream>>>(Wfc, WtFc, D_, H_);
  wtrans_kernel<<<dim3(H_ / 32, D_ / 128, E_), 256, 0, stream>>>(Wpj, WtPj, H_, D_);

  router_kernel<<<N_TOK / 4, 256, 0, stream>>>(x, cidx, dt, dd, drg, de, cemb, Wr, br,
                                               gate1, topk_e, topk_w);
  hist_kernel<<<R_ / 1024, 256, 0, stream>>>(topk_e, counts);
  build_tiles_kernel<<<1, 64, 0, stream>>>(counts, pbase, cursors, tile_expert, num_tiles);
  scatter_kernel<<<R_ / 256, 256, 0, stream>>>(topk_e, topk_w, pbase, cursors, prow_token, prow_w);

  for (int p = 0; p < NPH; p++) {
    int base = p * TPP;
    fc_gemm_kernel<<<dim3(H_ / BN, TPP), 256, 0, stream>>>(xbf, WtFc, bfc, prow_token,
                                                           tile_expert, num_tiles, zrow,
                                                           Hbuf, base);
    proj_gemm_kernel<<<dim3(D_ / BN, TPP), 256, 0, stream>>>(Hbuf, WtPj, bpj, prow_token,
                                                             prow_w, tile_expert, num_tiles,
                                                             out, base);
  }
}